// Round 1
// baseline (6735.046 us; speedup 1.0000x reference)
//
#include <hip/hip_runtime.h>
#include <math.h>

constexpr int NN   = 100000;   // nodes
constexpr int DIM  = 128;
constexpr int NE   = 3200000;  // edges
constexpr int NCLS = 40;
constexpr float EPSF = 1e-7f;

// ---------------- deg: in-degree over col (self-loop added later as +1) ----
__global__ void deg_kernel(const int* __restrict__ col, int* __restrict__ deg) {
    int i = blockIdx.x * blockDim.x + threadIdx.x;
    if (i < NE) atomicAdd(&deg[col[i]], 1);
}

// ---------------- h = concat(xE, logH, logS) @ W ; g = h * dinv ------------
__global__ __launch_bounds__(256) void h_kernel(
    const float* __restrict__ xE, const float* __restrict__ xH,
    const float* __restrict__ xS, const float* __restrict__ W,
    const int* __restrict__ deg, float* __restrict__ g) {

    __shared__ float Wl[3 * DIM * NCLS];   // 15360 f32 = 61.4 KB
    for (int i = threadIdx.x; i < 3 * DIM * NCLS; i += blockDim.x) Wl[i] = W[i];
    __syncthreads();

    int n = blockIdx.x * blockDim.x + threadIdx.x;
    if (n >= NN) return;

    float acc[NCLS];
#pragma unroll
    for (int c = 0; c < NCLS; ++c) acc[c] = 0.f;

    auto accum_row = [&](const float* __restrict__ xrow, int wbase,
                         float scale, bool zero_first) {
        const float4* x4 = reinterpret_cast<const float4*>(xrow);
        for (int k4 = 0; k4 < DIM / 4; ++k4) {
            float4 xv = x4[k4];
            float xs[4] = {xv.x, xv.y, xv.z, xv.w};
#pragma unroll
            for (int j = 0; j < 4; ++j) {
                int k = k4 * 4 + j;
                float xk = xs[j] * scale;
                if (zero_first && k4 == 0 && j == 0) xk = 0.f;
                const float4* wr =
                    reinterpret_cast<const float4*>(&Wl[(wbase + k) * NCLS]);
#pragma unroll
                for (int c4 = 0; c4 < NCLS / 4; ++c4) {
                    float4 wv = wr[c4];
                    acc[c4 * 4 + 0] = fmaf(xk, wv.x, acc[c4 * 4 + 0]);
                    acc[c4 * 4 + 1] = fmaf(xk, wv.y, acc[c4 * 4 + 1]);
                    acc[c4 * 4 + 2] = fmaf(xk, wv.z, acc[c4 * 4 + 2]);
                    acc[c4 * 4 + 3] = fmaf(xk, wv.w, acc[c4 * 4 + 3]);
                }
            }
        }
    };

    // Euclidean block: rows [0,128)
    accum_row(xE + (long)n * DIM, 0, 1.0f, false);

    // Lorentz logmap0: first comp -> 0, rest scaled by acosh(max(x0,1))/sqrt(max(x0^2-1,eps))
    {
        float x0 = xH[(long)n * DIM];
        float sH = acoshf(fmaxf(x0, 1.f)) * rsqrtf(fmaxf(x0 * x0 - 1.f, EPSF));
        accum_row(xH + (long)n * DIM, DIM, sH, true);
    }
    // Sphere logmap0: first comp -> 0, rest scaled by acos(clamp(c))/sqrt(max(1-c^2,eps))
    {
        float c0 = xS[(long)n * DIM];
        float cc = fminf(fmaxf(c0, -1.f), 1.f);
        float sS = acosf(cc) * rsqrtf(fmaxf(1.f - c0 * c0, EPSF));
        accum_row(xS + (long)n * DIM, 2 * DIM, sS, true);
    }

    float dinv = rsqrtf((float)(deg[n] + 1));   // +1 = self loop; always > 0
    float* gn = g + (long)n * NCLS;
#pragma unroll
    for (int c = 0; c < NCLS; ++c) gn[c] = acc[c] * dinv;
}

// ---------------- edge scatter: out[c] += g[r] ------------------------------
__global__ void scatter_kernel(const int* __restrict__ row,
                               const int* __restrict__ col,
                               const float* __restrict__ g,
                               float* __restrict__ out) {
    int e = blockIdx.x * blockDim.x + threadIdx.x;
    if (e >= NE) return;
    int r = row[e], c = col[e];
    const float4* gr = reinterpret_cast<const float4*>(g + (long)r * NCLS);
    float* oc = out + (long)c * NCLS;
#pragma unroll
    for (int q = 0; q < NCLS / 4; ++q) {
        float4 v = gr[q];
        atomicAdd(&oc[q * 4 + 0], v.x);
        atomicAdd(&oc[q * 4 + 1], v.y);
        atomicAdd(&oc[q * 4 + 2], v.z);
        atomicAdd(&oc[q * 4 + 3], v.w);
    }
}

// ---------------- out = dinv * (edge_acc + g)  (self-loop folded in) --------
__global__ void final_kernel(const int* __restrict__ deg,
                             const float* __restrict__ g,
                             float* __restrict__ out) {
    int n = blockIdx.x * blockDim.x + threadIdx.x;
    if (n >= NN) return;
    float dinv = rsqrtf((float)(deg[n] + 1));
    float4* on = reinterpret_cast<float4*>(out + (long)n * NCLS);
    const float4* gn = reinterpret_cast<const float4*>(g + (long)n * NCLS);
#pragma unroll
    for (int q = 0; q < NCLS / 4; ++q) {
        float4 o = on[q];
        float4 gv = gn[q];
        o.x = (o.x + gv.x) * dinv;
        o.y = (o.y + gv.y) * dinv;
        o.z = (o.z + gv.z) * dinv;
        o.w = (o.w + gv.w) * dinv;
        on[q] = o;
    }
}

extern "C" void kernel_launch(void* const* d_in, const int* in_sizes, int n_in,
                              void* d_out, int out_size, void* d_ws, size_t ws_size,
                              hipStream_t stream) {
    const float* xE = (const float*)d_in[0];
    const float* xH = (const float*)d_in[1];
    const float* xS = (const float*)d_in[2];
    const float* W  = (const float*)d_in[3];
    const int*   ei = (const int*)d_in[4];
    const int* row = ei;            // edge_index[0]
    const int* col = ei + NE;       // edge_index[1]
    float* out = (float*)d_out;

    int* deg = (int*)d_ws;
    size_t deg_bytes = ((size_t)NN * sizeof(int) + 255) & ~(size_t)255;
    float* g = (float*)((char*)d_ws + deg_bytes);

    hipMemsetAsync(d_ws, 0, deg_bytes, stream);
    hipMemsetAsync(d_out, 0, (size_t)NN * NCLS * sizeof(float), stream);

    deg_kernel<<<(NE + 255) / 256, 256, 0, stream>>>(col, deg);
    h_kernel<<<(NN + 255) / 256, 256, 0, stream>>>(xE, xH, xS, W, deg, g);
    scatter_kernel<<<(NE + 255) / 256, 256, 0, stream>>>(row, col, g, out);
    final_kernel<<<(NN + 255) / 256, 256, 0, stream>>>(deg, g, out);
}

// Round 2
// 771.869 us; speedup vs baseline: 8.7256x; 8.7256x over previous
//
#include <hip/hip_runtime.h>
#include <math.h>

constexpr int NN   = 100000;   // nodes
constexpr int DIM  = 128;
constexpr int NE   = 3200000;  // edges
constexpr int NCLS = 40;
constexpr float EPSF = 1e-7f;

// ---------------- deg: in-degree over col (self-loop added later as +1) ----
__global__ void deg_kernel(const int* __restrict__ col, int* __restrict__ deg) {
    int i = blockIdx.x * blockDim.x + threadIdx.x;
    if (i < NE) atomicAdd(&deg[col[i]], 1);
}

// ---------------- exclusive scan of deg -> offs[NN+1], single block --------
__global__ __launch_bounds__(1024) void scan_kernel(const int* __restrict__ deg,
                                                    int* __restrict__ offs) {
    __shared__ int part[1024];
    int t = threadIdx.x;
    constexpr int PER = (NN + 1023) / 1024;   // 98
    int lo = t * PER, hi = min(lo + PER, NN);
    int s = 0;
    for (int i = lo; i < hi; ++i) s += deg[i];
    part[t] = s;
    __syncthreads();
    for (int d = 1; d < 1024; d <<= 1) {
        int other = (t >= d) ? part[t - d] : 0;
        __syncthreads();
        part[t] += other;
        __syncthreads();
    }
    int run = part[t] - s;     // exclusive start of this chunk
    for (int i = lo; i < hi; ++i) { offs[i] = run; run += deg[i]; }
    if (t == 1023) offs[NN] = part[1023];
}

// ---------------- bucket fill: CSC edge list --------------------------------
__global__ void fill_kernel(const int* __restrict__ row, const int* __restrict__ col,
                            int* __restrict__ cursor, int* __restrict__ ebuf) {
    int e = blockIdx.x * blockDim.x + threadIdx.x;
    if (e >= NE) return;
    int c = col[e];
    int pos = atomicAdd(&cursor[c], 1);
    ebuf[pos] = row[e];
}

// ---------------- h = concat(xE, logH, logS) @ W ; g = h * dinv ------------
__global__ __launch_bounds__(256) void h_kernel(
    const float* __restrict__ xE, const float* __restrict__ xH,
    const float* __restrict__ xS, const float* __restrict__ W,
    const int* __restrict__ offs, float* __restrict__ g) {

    __shared__ float Wl[3 * DIM * NCLS];   // 15360 f32 = 61.4 KB
    for (int i = threadIdx.x; i < 3 * DIM * NCLS; i += blockDim.x) Wl[i] = W[i];
    __syncthreads();

    int n = blockIdx.x * blockDim.x + threadIdx.x;
    if (n >= NN) return;

    float acc[NCLS];
#pragma unroll
    for (int c = 0; c < NCLS; ++c) acc[c] = 0.f;

    auto accum_row = [&](const float* __restrict__ xrow, int wbase,
                         float scale, bool zero_first) {
        const float4* x4 = reinterpret_cast<const float4*>(xrow);
        for (int k4 = 0; k4 < DIM / 4; ++k4) {
            float4 xv = x4[k4];
            float xs[4] = {xv.x, xv.y, xv.z, xv.w};
#pragma unroll
            for (int j = 0; j < 4; ++j) {
                int k = k4 * 4 + j;
                float xk = xs[j] * scale;
                if (zero_first && k4 == 0 && j == 0) xk = 0.f;
                const float4* wr =
                    reinterpret_cast<const float4*>(&Wl[(wbase + k) * NCLS]);
#pragma unroll
                for (int c4 = 0; c4 < NCLS / 4; ++c4) {
                    float4 wv = wr[c4];
                    acc[c4 * 4 + 0] = fmaf(xk, wv.x, acc[c4 * 4 + 0]);
                    acc[c4 * 4 + 1] = fmaf(xk, wv.y, acc[c4 * 4 + 1]);
                    acc[c4 * 4 + 2] = fmaf(xk, wv.z, acc[c4 * 4 + 2]);
                    acc[c4 * 4 + 3] = fmaf(xk, wv.w, acc[c4 * 4 + 3]);
                }
            }
        }
    };

    accum_row(xE + (long)n * DIM, 0, 1.0f, false);
    {
        float x0 = xH[(long)n * DIM];
        float sH = acoshf(fmaxf(x0, 1.f)) * rsqrtf(fmaxf(x0 * x0 - 1.f, EPSF));
        accum_row(xH + (long)n * DIM, DIM, sH, true);
    }
    {
        float c0 = xS[(long)n * DIM];
        float cc = fminf(fmaxf(c0, -1.f), 1.f);
        float sS = acosf(cc) * rsqrtf(fmaxf(1.f - c0 * c0, EPSF));
        accum_row(xS + (long)n * DIM, 2 * DIM, sS, true);
    }

    float dinv = rsqrtf((float)(offs[n + 1] - offs[n] + 1));  // +1 self loop
    float* gn = g + (long)n * NCLS;
#pragma unroll
    for (int c = 0; c < NCLS; ++c) gn[c] = acc[c] * dinv;
}

// ---------------- gather: out[n][c] = dinv*(g[n][c] + sum_r g[r][c]) --------
__global__ __launch_bounds__(256) void gather_kernel(
    const int* __restrict__ offs, const int* __restrict__ ebuf,
    const float* __restrict__ g, float* __restrict__ out) {
    long t = (long)blockIdx.x * blockDim.x + threadIdx.x;
    if (t >= (long)NN * NCLS) return;
    int n = (int)(t / NCLS);
    int c = (int)(t - (long)n * NCLS);

    int s = offs[n], e = offs[n + 1];
    float dinv = rsqrtf((float)(e - s + 1));
    float acc = g[(long)n * NCLS + c];     // self loop (g already has dinv[n])
    float acc2 = 0.f;
    int j = s;
    for (; j + 1 < e; j += 2) {
        int r0 = ebuf[j], r1 = ebuf[j + 1];
        acc  += g[(long)r0 * NCLS + c];
        acc2 += g[(long)r1 * NCLS + c];
    }
    if (j < e) acc += g[(long)ebuf[j] * NCLS + c];
    out[t] = (acc + acc2) * dinv;
}

extern "C" void kernel_launch(void* const* d_in, const int* in_sizes, int n_in,
                              void* d_out, int out_size, void* d_ws, size_t ws_size,
                              hipStream_t stream) {
    const float* xE = (const float*)d_in[0];
    const float* xH = (const float*)d_in[1];
    const float* xS = (const float*)d_in[2];
    const float* W  = (const float*)d_in[3];
    const int*   ei = (const int*)d_in[4];
    const int* row = ei;            // edge_index[0]
    const int* col = ei + NE;       // edge_index[1]
    float* out = (float*)d_out;

    auto pad = [](size_t x) { return (x + 255) & ~(size_t)255; };
    char* p = (char*)d_ws;
    int* deg    = (int*)p;                 p += pad((size_t)NN * 4);
    int* offs   = (int*)p;                 p += pad((size_t)(NN + 1) * 4);
    int* cursor = (int*)p;                 p += pad((size_t)NN * 4);
    int* ebuf   = (int*)p;                 p += pad((size_t)NE * 4);
    float* g    = (float*)p;               // NN*NCLS floats

    hipMemsetAsync(deg, 0, (size_t)NN * 4, stream);

    deg_kernel<<<(NE + 255) / 256, 256, 0, stream>>>(col, deg);
    scan_kernel<<<1, 1024, 0, stream>>>(deg, offs);
    hipMemcpyAsync(cursor, offs, (size_t)NN * 4, hipMemcpyDeviceToDevice, stream);
    fill_kernel<<<(NE + 255) / 256, 256, 0, stream>>>(row, col, cursor, ebuf);
    h_kernel<<<(NN + 255) / 256, 256, 0, stream>>>(xE, xH, xS, W, offs, g);
    gather_kernel<<<((long)NN * NCLS + 255) / 256, 256, 0, stream>>>(offs, ebuf, g, out);
}

// Round 3
// 738.846 us; speedup vs baseline: 9.1156x; 1.0447x over previous
//
#include <hip/hip_runtime.h>
#include <math.h>

constexpr int NN   = 100000;   // nodes
constexpr int DIM  = 128;
constexpr int NE   = 3200000;  // edges
constexpr int NCLS = 40;
constexpr float EPSF = 1e-7f;
constexpr int RNG   = 8;                       // col ranges for fill
constexpr int RSPAN = NN / RNG;                // 12500

// ---------------- deg: in-degree over col (self-loop added later as +1) ----
__global__ void deg_kernel(const int4* __restrict__ col4, int* __restrict__ deg) {
    int i = blockIdx.x * blockDim.x + threadIdx.x;
    if (i < NE / 4) {
        int4 c = col4[i];
        atomicAdd(&deg[c.x], 1);
        atomicAdd(&deg[c.y], 1);
        atomicAdd(&deg[c.z], 1);
        atomicAdd(&deg[c.w], 1);
    }
}

// ------ exclusive scan of deg -> offs[NN+1]; also seeds cursor = offs ------
__global__ __launch_bounds__(1024) void scan_kernel(const int* __restrict__ deg,
                                                    int* __restrict__ offs,
                                                    int* __restrict__ cursor) {
    __shared__ int part[1024];
    int t = threadIdx.x;
    constexpr int PER = (NN + 1023) / 1024;   // 98
    int lo = t * PER, hi = min(lo + PER, NN);
    int s = 0;
    for (int i = lo; i < hi; ++i) s += deg[i];
    part[t] = s;
    __syncthreads();
    for (int d = 1; d < 1024; d <<= 1) {
        int other = (t >= d) ? part[t - d] : 0;
        __syncthreads();
        part[t] += other;
        __syncthreads();
    }
    int run = part[t] - s;     // exclusive start of this chunk
    for (int i = lo; i < hi; ++i) {
        offs[i] = run; cursor[i] = run; run += deg[i];
    }
    if (t == 1023) offs[NN] = part[1023];
}

// ------ bucket fill, col-range partitioned: writes stay L2-local ------------
__global__ void fill_kernel(const int* __restrict__ row, const int* __restrict__ col,
                            int* __restrict__ cursor, int* __restrict__ ebuf) {
    int r0 = blockIdx.y * RSPAN;
    int e = blockIdx.x * blockDim.x + threadIdx.x;
    if (e >= NE) return;
    int c = col[e];
    if ((unsigned)(c - r0) < (unsigned)RSPAN) {
        int pos = atomicAdd(&cursor[c], 1);
        ebuf[pos] = row[e];
    }
}

// ---------------- h = concat(xE, logH, logS) @ W ; g = h * dinv ------------
// W accessed at wave-uniform addresses -> scalar loads, no LDS needed.
__global__ __launch_bounds__(256) void h_kernel(
    const float* __restrict__ xE, const float* __restrict__ xH,
    const float* __restrict__ xS, const float* __restrict__ W,
    const int* __restrict__ offs, float* __restrict__ g) {

    int n = blockIdx.x * blockDim.x + threadIdx.x;
    if (n >= NN) return;

    float acc[NCLS];
#pragma unroll
    for (int c = 0; c < NCLS; ++c) acc[c] = 0.f;

    auto accum_row = [&](const float* __restrict__ xrow, int wbase,
                         float scale, bool zero_first) {
        const float4* x4 = reinterpret_cast<const float4*>(xrow);
        for (int k4 = 0; k4 < DIM / 4; ++k4) {
            float4 xv = x4[k4];
            float xs[4] = {xv.x, xv.y, xv.z, xv.w};
#pragma unroll
            for (int j = 0; j < 4; ++j) {
                int k = k4 * 4 + j;
                float xk = xs[j] * scale;
                if (zero_first && k4 == 0 && j == 0) xk = 0.f;
                const float4* wr =
                    reinterpret_cast<const float4*>(&W[(wbase + k) * NCLS]);
#pragma unroll
                for (int c4 = 0; c4 < NCLS / 4; ++c4) {
                    float4 wv = wr[c4];
                    acc[c4 * 4 + 0] = fmaf(xk, wv.x, acc[c4 * 4 + 0]);
                    acc[c4 * 4 + 1] = fmaf(xk, wv.y, acc[c4 * 4 + 1]);
                    acc[c4 * 4 + 2] = fmaf(xk, wv.z, acc[c4 * 4 + 2]);
                    acc[c4 * 4 + 3] = fmaf(xk, wv.w, acc[c4 * 4 + 3]);
                }
            }
        }
    };

    accum_row(xE + (long)n * DIM, 0, 1.0f, false);
    {
        float x0 = xH[(long)n * DIM];
        float sH = acoshf(fmaxf(x0, 1.f)) * rsqrtf(fmaxf(x0 * x0 - 1.f, EPSF));
        accum_row(xH + (long)n * DIM, DIM, sH, true);
    }
    {
        float c0 = xS[(long)n * DIM];
        float cc = fminf(fmaxf(c0, -1.f), 1.f);
        float sS = acosf(cc) * rsqrtf(fmaxf(1.f - c0 * c0, EPSF));
        accum_row(xS + (long)n * DIM, 2 * DIM, sS, true);
    }

    float dinv = rsqrtf((float)(offs[n + 1] - offs[n] + 1));  // +1 self loop
    float* gn = g + (long)n * NCLS;
#pragma unroll
    for (int c = 0; c < NCLS; ++c) gn[c] = acc[c] * dinv;
}

// ---------------- gather: out[n][c] = dinv*(g[n][c] + sum_r g[r][c]) --------
__global__ __launch_bounds__(256) void gather_kernel(
    const int* __restrict__ offs, const int* __restrict__ ebuf,
    const float* __restrict__ g, float* __restrict__ out) {
    long t = (long)blockIdx.x * blockDim.x + threadIdx.x;
    if (t >= (long)NN * NCLS) return;
    int n = (int)(t / NCLS);
    int c = (int)(t - (long)n * NCLS);

    int s = offs[n], e = offs[n + 1];
    float dinv = rsqrtf((float)(e - s + 1));
    float acc = g[(long)n * NCLS + c];     // self loop (g already has dinv[n])
    float acc2 = 0.f;
    int j = s;
    for (; j + 1 < e; j += 2) {
        int r0 = ebuf[j], r1 = ebuf[j + 1];
        acc  += g[(long)r0 * NCLS + c];
        acc2 += g[(long)r1 * NCLS + c];
    }
    if (j < e) acc += g[(long)ebuf[j] * NCLS + c];
    out[t] = (acc + acc2) * dinv;
}

extern "C" void kernel_launch(void* const* d_in, const int* in_sizes, int n_in,
                              void* d_out, int out_size, void* d_ws, size_t ws_size,
                              hipStream_t stream) {
    const float* xE = (const float*)d_in[0];
    const float* xH = (const float*)d_in[1];
    const float* xS = (const float*)d_in[2];
    const float* W  = (const float*)d_in[3];
    const int*   ei = (const int*)d_in[4];
    const int* row = ei;            // edge_index[0]
    const int* col = ei + NE;       // edge_index[1]
    float* out = (float*)d_out;

    auto pad = [](size_t x) { return (x + 255) & ~(size_t)255; };
    char* p = (char*)d_ws;
    int* deg    = (int*)p;                 p += pad((size_t)NN * 4);
    int* offs   = (int*)p;                 p += pad((size_t)(NN + 1) * 4);
    int* cursor = (int*)p;                 p += pad((size_t)NN * 4);
    int* ebuf   = (int*)p;                 p += pad((size_t)NE * 4);
    float* g    = (float*)p;               // NN*NCLS floats

    hipMemsetAsync(deg, 0, (size_t)NN * 4, stream);

    deg_kernel<<<(NE / 4 + 255) / 256, 256, 0, stream>>>((const int4*)col, deg);
    scan_kernel<<<1, 1024, 0, stream>>>(deg, offs, cursor);
    fill_kernel<<<dim3((NE + 255) / 256, RNG), 256, 0, stream>>>(row, col, cursor, ebuf);
    h_kernel<<<(NN + 255) / 256, 256, 0, stream>>>(xE, xH, xS, W, offs, g);
    gather_kernel<<<((long)NN * NCLS + 255) / 256, 256, 0, stream>>>(offs, ebuf, g, out);
}

// Round 4
// 519.352 us; speedup vs baseline: 12.9682x; 1.4226x over previous
//
#include <hip/hip_runtime.h>
#include <math.h>

constexpr int NN   = 100000;   // nodes
constexpr int DIM  = 128;
constexpr int NE   = 3200000;  // edges
constexpr int NCLS = 40;
constexpr float EPSF = 1e-7f;
constexpr int RNG   = 8;                       // col ranges for fill
constexpr int RSPAN = NN / RNG;                // 12500

constexpr int SCHUNK = 1024;                   // elems per scan block
constexpr int SNB = (NN + SCHUNK - 1) / SCHUNK; // 98 scan blocks

// ---------------- deg: in-degree over col (self-loop added later as +1) ----
__global__ void deg_kernel(const int4* __restrict__ col4, int* __restrict__ deg) {
    int i = blockIdx.x * blockDim.x + threadIdx.x;
    if (i < NE / 4) {
        int4 c = col4[i];
        atomicAdd(&deg[c.x], 1);
        atomicAdd(&deg[c.y], 1);
        atomicAdd(&deg[c.z], 1);
        atomicAdd(&deg[c.w], 1);
    }
}

// ---- scan phase 1: per-block local exclusive scan + block sums -------------
__global__ __launch_bounds__(256) void scan1_kernel(const int* __restrict__ deg,
                                                    int* __restrict__ offs,
                                                    int* __restrict__ partial) {
    __shared__ int ts[256];
    int t = threadIdx.x;
    int base = blockIdx.x * SCHUNK + t * 4;
    int v[4] = {0, 0, 0, 0};
    if (base + 3 < NN) {
        int4 d = *reinterpret_cast<const int4*>(deg + base);
        v[0] = d.x; v[1] = d.y; v[2] = d.z; v[3] = d.w;
    } else {
        for (int j = 0; j < 4; ++j) if (base + j < NN) v[j] = deg[base + j];
    }
    int s = v[0] + v[1] + v[2] + v[3];
    ts[t] = s;
    __syncthreads();
    // Hillis-Steele inclusive scan over 256 thread sums
    for (int d = 1; d < 256; d <<= 1) {
        int o = (t >= d) ? ts[t - d] : 0;
        __syncthreads();
        ts[t] += o;
        __syncthreads();
    }
    int run = ts[t] - s;   // exclusive prefix of this thread within block
    int w[4];
    w[0] = run;
    w[1] = run + v[0];
    w[2] = w[1] + v[1];
    w[3] = w[2] + v[2];
    if (base + 3 < NN) {
        *reinterpret_cast<int4*>(offs + base) = make_int4(w[0], w[1], w[2], w[3]);
    } else {
        for (int j = 0; j < 4; ++j) if (base + j < NN) offs[base + j] = w[j];
    }
    if (t == 255) partial[blockIdx.x] = ts[255];
}

// ---- scan phase 2: exclusive scan of the 98 block sums (one small block) ---
__global__ __launch_bounds__(128) void scan2_kernel(int* __restrict__ partial,
                                                    int* __restrict__ offs_last) {
    __shared__ int ps[128];
    int t = threadIdx.x;
    int v = (t < SNB) ? partial[t] : 0;
    ps[t] = v;
    __syncthreads();
    for (int d = 1; d < 128; d <<= 1) {
        int o = (t >= d) ? ps[t - d] : 0;
        __syncthreads();
        ps[t] += o;
        __syncthreads();
    }
    if (t < SNB) partial[t] = ps[t] - v;        // exclusive
    if (t == 127) *offs_last = ps[127];         // total = offs[NN] (=NE)
}

// ---- scan phase 3: add block offsets; seed cursor ---------------------------
__global__ __launch_bounds__(256) void scan3_kernel(int* __restrict__ offs,
                                                    int* __restrict__ cursor,
                                                    const int* __restrict__ partial) {
    int i = blockIdx.x * blockDim.x + threadIdx.x;
    if (i >= NN) return;
    int o = offs[i] + partial[i >> 10];
    offs[i] = o;
    cursor[i] = o;
}

// ------ bucket fill, col-range partitioned: writes stay L2-local ------------
__global__ void fill_kernel(const int* __restrict__ row, const int* __restrict__ col,
                            int* __restrict__ cursor, int* __restrict__ ebuf) {
    int r0 = blockIdx.y * RSPAN;
    int e = blockIdx.x * blockDim.x + threadIdx.x;
    if (e >= NE) return;
    int c = col[e];
    if ((unsigned)(c - r0) < (unsigned)RSPAN) {
        int pos = atomicAdd(&cursor[c], 1);
        ebuf[pos] = row[e];
    }
}

// ---------------- h = concat(xE, logH, logS) @ W ; g = h * dinv ------------
__global__ __launch_bounds__(256) void h_kernel(
    const float* __restrict__ xE, const float* __restrict__ xH,
    const float* __restrict__ xS, const float* __restrict__ W,
    const int* __restrict__ offs, float* __restrict__ g) {

    int n = blockIdx.x * blockDim.x + threadIdx.x;
    if (n >= NN) return;

    float acc[NCLS];
#pragma unroll
    for (int c = 0; c < NCLS; ++c) acc[c] = 0.f;

    auto accum_row = [&](const float* __restrict__ xrow, int wbase,
                         float scale, bool zero_first) {
        const float4* x4 = reinterpret_cast<const float4*>(xrow);
        for (int k4 = 0; k4 < DIM / 4; ++k4) {
            float4 xv = x4[k4];
            float xs[4] = {xv.x, xv.y, xv.z, xv.w};
#pragma unroll
            for (int j = 0; j < 4; ++j) {
                int k = k4 * 4 + j;
                float xk = xs[j] * scale;
                if (zero_first && k4 == 0 && j == 0) xk = 0.f;
                const float4* wr =
                    reinterpret_cast<const float4*>(&W[(wbase + k) * NCLS]);
#pragma unroll
                for (int c4 = 0; c4 < NCLS / 4; ++c4) {
                    float4 wv = wr[c4];
                    acc[c4 * 4 + 0] = fmaf(xk, wv.x, acc[c4 * 4 + 0]);
                    acc[c4 * 4 + 1] = fmaf(xk, wv.y, acc[c4 * 4 + 1]);
                    acc[c4 * 4 + 2] = fmaf(xk, wv.z, acc[c4 * 4 + 2]);
                    acc[c4 * 4 + 3] = fmaf(xk, wv.w, acc[c4 * 4 + 3]);
                }
            }
        }
    };

    accum_row(xE + (long)n * DIM, 0, 1.0f, false);
    {
        float x0 = xH[(long)n * DIM];
        float sH = acoshf(fmaxf(x0, 1.f)) * rsqrtf(fmaxf(x0 * x0 - 1.f, EPSF));
        accum_row(xH + (long)n * DIM, DIM, sH, true);
    }
    {
        float c0 = xS[(long)n * DIM];
        float cc = fminf(fmaxf(c0, -1.f), 1.f);
        float sS = acosf(cc) * rsqrtf(fmaxf(1.f - c0 * c0, EPSF));
        accum_row(xS + (long)n * DIM, 2 * DIM, sS, true);
    }

    float dinv = rsqrtf((float)(offs[n + 1] - offs[n] + 1));  // +1 self loop
    float* gn = g + (long)n * NCLS;
#pragma unroll
    for (int c = 0; c < NCLS; ++c) gn[c] = acc[c] * dinv;
}

// ---------------- gather: out[n][c] = dinv*(g[n][c] + sum_r g[r][c]) --------
__global__ __launch_bounds__(256) void gather_kernel(
    const int* __restrict__ offs, const int* __restrict__ ebuf,
    const float* __restrict__ g, float* __restrict__ out) {
    long t = (long)blockIdx.x * blockDim.x + threadIdx.x;
    if (t >= (long)NN * NCLS) return;
    int n = (int)(t / NCLS);
    int c = (int)(t - (long)n * NCLS);

    int s = offs[n], e = offs[n + 1];
    float dinv = rsqrtf((float)(e - s + 1));
    float acc = g[(long)n * NCLS + c];     // self loop (g already has dinv[n])
    float acc2 = 0.f;
    int j = s;
    for (; j + 1 < e; j += 2) {
        int r0 = ebuf[j], r1 = ebuf[j + 1];
        acc  += g[(long)r0 * NCLS + c];
        acc2 += g[(long)r1 * NCLS + c];
    }
    if (j < e) acc += g[(long)ebuf[j] * NCLS + c];
    out[t] = (acc + acc2) * dinv;
}

extern "C" void kernel_launch(void* const* d_in, const int* in_sizes, int n_in,
                              void* d_out, int out_size, void* d_ws, size_t ws_size,
                              hipStream_t stream) {
    const float* xE = (const float*)d_in[0];
    const float* xH = (const float*)d_in[1];
    const float* xS = (const float*)d_in[2];
    const float* W  = (const float*)d_in[3];
    const int*   ei = (const int*)d_in[4];
    const int* row = ei;            // edge_index[0]
    const int* col = ei + NE;       // edge_index[1]
    float* out = (float*)d_out;

    auto pad = [](size_t x) { return (x + 255) & ~(size_t)255; };
    char* p = (char*)d_ws;
    int* deg     = (int*)p;                p += pad((size_t)NN * 4);
    int* offs    = (int*)p;                p += pad((size_t)(NN + 1) * 4);
    int* cursor  = (int*)p;                p += pad((size_t)NN * 4);
    int* partial = (int*)p;                p += pad((size_t)SNB * 4);
    int* ebuf    = (int*)p;                p += pad((size_t)NE * 4);
    float* g     = (float*)p;              // NN*NCLS floats

    hipMemsetAsync(deg, 0, (size_t)NN * 4, stream);

    deg_kernel<<<(NE / 4 + 255) / 256, 256, 0, stream>>>((const int4*)col, deg);
    scan1_kernel<<<SNB, 256, 0, stream>>>(deg, offs, partial);
    scan2_kernel<<<1, 128, 0, stream>>>(partial, offs + NN);
    scan3_kernel<<<(NN + 255) / 256, 256, 0, stream>>>(offs, cursor, partial);
    fill_kernel<<<dim3((NE + 255) / 256, RNG), 256, 0, stream>>>(row, col, cursor, ebuf);
    h_kernel<<<(NN + 255) / 256, 256, 0, stream>>>(xE, xH, xS, W, offs, g);
    gather_kernel<<<((long)NN * NCLS + 255) / 256, 256, 0, stream>>>(offs, ebuf, g, out);
}

// Round 5
// 472.250 us; speedup vs baseline: 14.2616x; 1.0997x over previous
//
#include <hip/hip_runtime.h>
#include <math.h>

constexpr int NN   = 100000;   // nodes
constexpr int DIM  = 128;
constexpr int NE   = 3200000;  // edges
constexpr int NCLS = 40;
constexpr float EPSF = 1e-7f;
constexpr int RNG   = 8;                        // col ranges == XCD count
constexpr int RSPAN = NN / RNG;                 // 12500
constexpr int FCH   = NE / 256;                 // fill chunks (exact: 12500)

constexpr int SCHUNK = 1024;                    // elems per scan block
constexpr int SNB = (NN + SCHUNK - 1) / SCHUNK; // 98 scan blocks

// ---------------- deg: in-degree over col (self-loop added later as +1) ----
__global__ void deg_kernel(const int4* __restrict__ col4, int* __restrict__ deg) {
    int i = blockIdx.x * blockDim.x + threadIdx.x;
    if (i < NE / 4) {
        int4 c = col4[i];
        atomicAdd(&deg[c.x], 1);
        atomicAdd(&deg[c.y], 1);
        atomicAdd(&deg[c.z], 1);
        atomicAdd(&deg[c.w], 1);
    }
}

// ---- scan phase 1: per-block local exclusive scan + block sums -------------
__global__ __launch_bounds__(256) void scan1_kernel(const int* __restrict__ deg,
                                                    int* __restrict__ offs,
                                                    int* __restrict__ partial) {
    __shared__ int ts[256];
    int t = threadIdx.x;
    int base = blockIdx.x * SCHUNK + t * 4;
    int v[4] = {0, 0, 0, 0};
    if (base + 3 < NN) {
        int4 d = *reinterpret_cast<const int4*>(deg + base);
        v[0] = d.x; v[1] = d.y; v[2] = d.z; v[3] = d.w;
    } else {
        for (int j = 0; j < 4; ++j) if (base + j < NN) v[j] = deg[base + j];
    }
    int s = v[0] + v[1] + v[2] + v[3];
    ts[t] = s;
    __syncthreads();
    for (int d = 1; d < 256; d <<= 1) {
        int o = (t >= d) ? ts[t - d] : 0;
        __syncthreads();
        ts[t] += o;
        __syncthreads();
    }
    int run = ts[t] - s;
    int w[4];
    w[0] = run;
    w[1] = run + v[0];
    w[2] = w[1] + v[1];
    w[3] = w[2] + v[2];
    if (base + 3 < NN) {
        *reinterpret_cast<int4*>(offs + base) = make_int4(w[0], w[1], w[2], w[3]);
    } else {
        for (int j = 0; j < 4; ++j) if (base + j < NN) offs[base + j] = w[j];
    }
    if (t == 255) partial[blockIdx.x] = ts[255];
}

// ---- scan phase 2: exclusive scan of the 98 block sums ---------------------
__global__ __launch_bounds__(128) void scan2_kernel(int* __restrict__ partial,
                                                    int* __restrict__ offs_last) {
    __shared__ int ps[128];
    int t = threadIdx.x;
    int v = (t < SNB) ? partial[t] : 0;
    ps[t] = v;
    __syncthreads();
    for (int d = 1; d < 128; d <<= 1) {
        int o = (t >= d) ? ps[t - d] : 0;
        __syncthreads();
        ps[t] += o;
        __syncthreads();
    }
    if (t < SNB) partial[t] = ps[t] - v;
    if (t == 127) *offs_last = ps[127];
}

// ---- scan phase 3: add block offsets; seed cursor ---------------------------
__global__ __launch_bounds__(256) void scan3_kernel(int* __restrict__ offs,
                                                    int* __restrict__ cursor,
                                                    const int* __restrict__ partial) {
    int i = blockIdx.x * blockDim.x + threadIdx.x;
    if (i >= NN) return;
    int o = offs[i] + partial[i >> 10];
    offs[i] = o;
    cursor[i] = o;
}

// ------ bucket fill, XCD-spatial col-range partitioning ----------------------
// range = bid % 8 == XCC_ID (round-robin dispatch): all writes to ebuf window r
// come from XCD r only -> each line dirty in exactly one L2 -> single writeback.
__global__ __launch_bounds__(256) void fill_kernel(const int* __restrict__ row,
                                                   const int* __restrict__ col,
                                                   int* __restrict__ cursor,
                                                   int* __restrict__ ebuf) {
    int b = blockIdx.x;
    int range = b & (RNG - 1);
    int chunk = b >> 3;
    int e = chunk * 256 + threadIdx.x;      // FCH*256 == NE exactly
    int r0 = range * RSPAN;
    int c = col[e];
    if ((unsigned)(c - r0) < (unsigned)RSPAN) {
        int pos = atomicAdd(&cursor[c], 1);
        ebuf[pos] = row[e];
    }
}

// ---------------- h = concat(xE, logH, logS) @ W ; g = h * dinv ------------
__global__ __launch_bounds__(256) void h_kernel(
    const float* __restrict__ xE, const float* __restrict__ xH,
    const float* __restrict__ xS, const float* __restrict__ W,
    const int* __restrict__ offs, float* __restrict__ g) {

    int n = blockIdx.x * blockDim.x + threadIdx.x;
    if (n >= NN) return;

    float acc[NCLS];
#pragma unroll
    for (int c = 0; c < NCLS; ++c) acc[c] = 0.f;

    auto accum_row = [&](const float* __restrict__ xrow, int wbase,
                         float scale, bool zero_first) {
        const float4* x4 = reinterpret_cast<const float4*>(xrow);
        for (int k4 = 0; k4 < DIM / 4; ++k4) {
            float4 xv = x4[k4];
            float xs[4] = {xv.x, xv.y, xv.z, xv.w};
#pragma unroll
            for (int j = 0; j < 4; ++j) {
                int k = k4 * 4 + j;
                float xk = xs[j] * scale;
                if (zero_first && k4 == 0 && j == 0) xk = 0.f;
                const float4* wr =
                    reinterpret_cast<const float4*>(&W[(wbase + k) * NCLS]);
#pragma unroll
                for (int c4 = 0; c4 < NCLS / 4; ++c4) {
                    float4 wv = wr[c4];
                    acc[c4 * 4 + 0] = fmaf(xk, wv.x, acc[c4 * 4 + 0]);
                    acc[c4 * 4 + 1] = fmaf(xk, wv.y, acc[c4 * 4 + 1]);
                    acc[c4 * 4 + 2] = fmaf(xk, wv.z, acc[c4 * 4 + 2]);
                    acc[c4 * 4 + 3] = fmaf(xk, wv.w, acc[c4 * 4 + 3]);
                }
            }
        }
    };

    accum_row(xE + (long)n * DIM, 0, 1.0f, false);
    {
        float x0 = xH[(long)n * DIM];
        float sH = acoshf(fmaxf(x0, 1.f)) * rsqrtf(fmaxf(x0 * x0 - 1.f, EPSF));
        accum_row(xH + (long)n * DIM, DIM, sH, true);
    }
    {
        float c0 = xS[(long)n * DIM];
        float cc = fminf(fmaxf(c0, -1.f), 1.f);
        float sS = acosf(cc) * rsqrtf(fmaxf(1.f - c0 * c0, EPSF));
        accum_row(xS + (long)n * DIM, 2 * DIM, sS, true);
    }

    float dinv = rsqrtf((float)(offs[n + 1] - offs[n] + 1));  // +1 self loop
    float* gn = g + (long)n * NCLS;
#pragma unroll
    for (int c = 0; c < NCLS; ++c) gn[c] = acc[c] * dinv;
}

// ------ gather: float2 per thread (20 threads/node), 2x unrolled edge loop ---
__global__ __launch_bounds__(256) void gather_kernel(
    const int* __restrict__ offs, const int* __restrict__ ebuf,
    const float* __restrict__ g, float* __restrict__ out) {
    int t = blockIdx.x * blockDim.x + threadIdx.x;
    if (t >= NN * (NCLS / 2)) return;
    int n  = t / (NCLS / 2);
    int c2 = t - n * (NCLS / 2);

    int s = offs[n], e = offs[n + 1];
    float dinv = rsqrtf((float)(e - s + 1));
    const float2* g2 = reinterpret_cast<const float2*>(g);
    float2 sv = g2[n * (NCLS / 2) + c2];        // self loop (has dinv[n] folded)
    float ax = sv.x, ay = sv.y, bx = 0.f, by = 0.f;
    int j = s;
    for (; j + 1 < e; j += 2) {
        int r0 = ebuf[j], r1 = ebuf[j + 1];
        float2 v0 = g2[r0 * (NCLS / 2) + c2];
        float2 v1 = g2[r1 * (NCLS / 2) + c2];
        ax += v0.x; ay += v0.y;
        bx += v1.x; by += v1.y;
    }
    if (j < e) {
        float2 v = g2[ebuf[j] * (NCLS / 2) + c2];
        ax += v.x; ay += v.y;
    }
    float2 o;
    o.x = (ax + bx) * dinv;
    o.y = (ay + by) * dinv;
    reinterpret_cast<float2*>(out)[t] = o;
}

extern "C" void kernel_launch(void* const* d_in, const int* in_sizes, int n_in,
                              void* d_out, int out_size, void* d_ws, size_t ws_size,
                              hipStream_t stream) {
    const float* xE = (const float*)d_in[0];
    const float* xH = (const float*)d_in[1];
    const float* xS = (const float*)d_in[2];
    const float* W  = (const float*)d_in[3];
    const int*   ei = (const int*)d_in[4];
    const int* row = ei;            // edge_index[0]
    const int* col = ei + NE;       // edge_index[1]
    float* out = (float*)d_out;

    auto pad = [](size_t x) { return (x + 255) & ~(size_t)255; };
    char* p = (char*)d_ws;
    int* deg     = (int*)p;                p += pad((size_t)NN * 4);
    int* offs    = (int*)p;                p += pad((size_t)(NN + 1) * 4);
    int* cursor  = (int*)p;                p += pad((size_t)NN * 4);
    int* partial = (int*)p;                p += pad((size_t)SNB * 4);
    int* ebuf    = (int*)p;                p += pad((size_t)NE * 4);
    float* g     = (float*)p;              // NN*NCLS floats

    hipMemsetAsync(deg, 0, (size_t)NN * 4, stream);

    deg_kernel<<<(NE / 4 + 255) / 256, 256, 0, stream>>>((const int4*)col, deg);
    scan1_kernel<<<SNB, 256, 0, stream>>>(deg, offs, partial);
    scan2_kernel<<<1, 128, 0, stream>>>(partial, offs + NN);
    scan3_kernel<<<(NN + 255) / 256, 256, 0, stream>>>(offs, cursor, partial);
    fill_kernel<<<FCH * RNG, 256, 0, stream>>>(row, col, cursor, ebuf);
    h_kernel<<<(NN + 255) / 256, 256, 0, stream>>>(xE, xH, xS, W, offs, g);
    gather_kernel<<<(NN * (NCLS / 2) + 255) / 256, 256, 0, stream>>>(offs, ebuf, g, out);
}